// Round 1
// baseline (57.738 us; speedup 1.0000x reference)
//
#include <hip/hip_runtime.h>
#include <math.h>

#define N_   2
#define C_   256
#define H_   16
#define W_   16
#define T_   8
#define P_   256      // H_*W_
#define PAD_ 3

// ws layout (floats): base[N_*P_] (indexed n*256 + h*16 + w), areas[N_*T_]

__global__ void k1_base_areas(const float* __restrict__ feat,
                              const float* __restrict__ wt,
                              const int* __restrict__ tgt,
                              float* __restrict__ ws,
                              float* __restrict__ out) {
    int b = blockIdx.x;
    int tid = threadIdx.x;
    __shared__ float red[256];

    if (b < N_ * H_ * W_) {
        // base[n,h,w] = sum_c sum_{kh,kw} feat[n,c,h-3+kh,w-3+kw] * wt[c,kh,kw]
        int n = b >> 8;
        int h = (b >> 4) & 15;
        int w = b & 15;
        int c = tid;                       // one channel per thread
        const float* fp = feat + (size_t)(n * C_ + c) * (H_ * W_);
        const float* wp = wt + c * 49;
        float acc = 0.f;
        #pragma unroll
        for (int kh = 0; kh < 7; ++kh) {
            int y = h - PAD_ + kh;
            if (y < 0 || y >= H_) continue;
            #pragma unroll
            for (int kw = 0; kw < 7; ++kw) {
                int x = w - PAD_ + kw;
                if (x < 0 || x >= W_) continue;
                acc += fp[y * W_ + x] * wp[kh * 7 + kw];
            }
        }
        red[tid] = acc;
        __syncthreads();
        for (int s = 128; s > 0; s >>= 1) {
            if (tid < s) red[tid] += red[tid + s];
            __syncthreads();
        }
        if (tid == 0) ws[b] = red[0];
    } else {
        // areas[n,tt] = sum over pixels of targets[n,tt,:,:]
        int i = b - N_ * H_ * W_;          // 0..15
        int n = i >> 3, tt = i & 7;
        red[tid] = (float)tgt[(n * T_ + tt) * P_ + tid];
        __syncthreads();
        for (int s = 128; s > 0; s >>= 1) {
            if (tid < s) red[tid] += red[tid + s];
            __syncthreads();
        }
        if (tid == 0) {
            ws[N_ * P_ + i] = red[0];
            if (i == 0) out[0] = 0.f;      // re-zero scalar output every launch
        }
    }
}

__global__ void k2_loss(const float* __restrict__ wt,
                        const float* __restrict__ bias,
                        const int* __restrict__ tgt,
                        const float* __restrict__ ws,
                        float* __restrict__ out) {
    int b = blockIdx.x;                    // n*256 + p
    int tid = threadIdx.x;                 // pixel h*16 + w
    int n = b >> 8;
    int p = b & 255;
    int ph = p >> 4, pw = p & 15;
    int h = tid >> 4, w = tid & 15;

    __shared__ float s_area[T_];
    __shared__ int   s_on[T_];
    __shared__ float red[256];

    if (tid < T_) {
        s_on[tid]   = tgt[(n * T_ + tid) * P_ + p];      // target value at pixel p
        s_area[tid] = ws[N_ * P_ + n * T_ + tid];
    }
    __syncthreads();

    // m = sigmoid(base[n,h,w] + K[ph-h+3, pw-w+3] + b)
    float base = ws[n * P_ + tid];
    int dh = ph - h + PAD_;
    int dw = pw - w + PAD_;
    float kc = 0.f;
    if ((unsigned)dh < 7u && (unsigned)dw < 7u)
        kc = wt[C_ * 49 + dh * 7 + dw];                  // onehot channel weights
    float xv = base + kc + bias[0];
    float m = 1.f / (1.f + expf(-xv));

    // cnt and first-argmin over areas of "on" targets (jnp.argmin semantics)
    int cnt = 0;
    float best = 3.402823466e38f;
    int idx = 0;
    #pragma unroll
    for (int tt = 0; tt < T_; ++tt) {
        int on = s_on[tt];
        cnt += on;
        if (on > 0 && s_area[tt] < best) { best = s_area[tt]; idx = tt; }
    }

    float contrib;
    if (cnt > 0) {
        float ch = (float)tgt[(n * T_ + idx) * P_ + tid];
        contrib = fabsf(m - ch);
    } else {
        int st = 0;
        #pragma unroll
        for (int tt = 0; tt < T_; ++tt) st += tgt[(n * T_ + tt) * P_ + tid];
        contrib = (float)st * m;
    }

    red[tid] = contrib;
    __syncthreads();
    for (int s = 128; s > 0; s >>= 1) {
        if (tid < s) red[tid] += red[tid + s];
        __syncthreads();
    }
    if (tid == 0) atomicAdd(out, red[0] * (1.0f / 256.0f));
}

extern "C" void kernel_launch(void* const* d_in, const int* in_sizes, int n_in,
                              void* d_out, int out_size, void* d_ws, size_t ws_size,
                              hipStream_t stream) {
    const float* feat = (const float*)d_in[0];
    const float* wt   = (const float*)d_in[1];
    const float* bias = (const float*)d_in[2];
    const int*   tgt  = (const int*)d_in[3];
    float* out = (float*)d_out;
    float* ws  = (float*)d_ws;

    k1_base_areas<<<N_ * H_ * W_ + N_ * T_, 256, 0, stream>>>(feat, wt, tgt, ws, out);
    k2_loss<<<N_ * P_, 256, 0, stream>>>(wt, bias, tgt, ws, out);
}

// Round 2
// 49.725 us; speedup vs baseline: 1.1612x; 1.1612x over previous
//
#include <hip/hip_runtime.h>
#include <math.h>

#define N_    2
#define C_    256
#define H_    16
#define W_    16
#define T_    8
#define P_    256      // H_*W_
#define PAD_  3
#define CHUNKS_   16
#define CPC_      16   // channels per chunk (CHUNKS_*CPC_ == C_)
#define NB_BASE_  (N_ * CHUNKS_)   // 32 base blocks

// ws layout (floats):
//   base_part[N_*CHUNKS_*P_]  : partial conv sums, indexed (n*CHUNKS_+chunk)*P_ + pix
//   areas[N_*T_]              : at offset N_*CHUNKS_*P_

__global__ void k1_base_areas(const float* __restrict__ feat,
                              const float* __restrict__ wt,
                              const int* __restrict__ tgt,
                              float* __restrict__ ws,
                              float* __restrict__ out) {
    int b = blockIdx.x;
    int tid = threadIdx.x;

    if (b < NB_BASE_) {
        // partial base[n,pix] over 16 channels, thread = output pixel
        __shared__ float plane[CPC_ * P_];   // 16 channel planes, 16 KB
        __shared__ float wsm[CPC_ * 49];     // their weights
        int n = b / CHUNKS_;
        int chunk = b % CHUNKS_;
        int c0 = chunk * CPC_;

        // stage 16 contiguous channel planes: 4096 floats = 1024 float4
        const float4* src4 = (const float4*)(feat + (size_t)(n * C_ + c0) * P_);
        float4* dst4 = (float4*)plane;
        #pragma unroll
        for (int j = 0; j < 4; ++j)
            dst4[tid + j * 256] = src4[tid + j * 256];
        // stage weights: 16*49 = 784 floats (not 16B-aligned -> scalar coalesced)
        const float* wp = wt + c0 * 49;
        for (int i = tid; i < CPC_ * 49; i += 256)
            wsm[i] = wp[i];
        __syncthreads();

        int h = tid >> 4, w = tid & 15;
        float acc = 0.f;
        for (int c = 0; c < CPC_; ++c) {
            const float* pl = plane + c * P_;
            const float* wc = wsm + c * 49;
            #pragma unroll
            for (int kh = 0; kh < 7; ++kh) {
                int y = h - PAD_ + kh;
                if (y < 0 || y >= H_) continue;
                #pragma unroll
                for (int kw = 0; kw < 7; ++kw) {
                    int x = w - PAD_ + kw;
                    if (x < 0 || x >= W_) continue;
                    acc += pl[y * W_ + x] * wc[kh * 7 + kw];
                }
            }
        }
        ws[(size_t)b * P_ + tid] = acc;
    } else {
        // areas[n,tt] = sum over pixels of targets[n,tt,:,:]
        __shared__ float red[256];
        int i = b - NB_BASE_;              // 0..15
        int n = i >> 3, tt = i & 7;
        red[tid] = (float)tgt[(n * T_ + tt) * P_ + tid];
        __syncthreads();
        for (int s = 128; s > 0; s >>= 1) {
            if (tid < s) red[tid] += red[tid + s];
            __syncthreads();
        }
        if (tid == 0) {
            ws[NB_BASE_ * P_ + i] = red[0];
            if (i == 0) out[0] = 0.f;      // re-zero scalar output every launch
        }
    }
}

__global__ void k2_loss(const float* __restrict__ wt,
                        const float* __restrict__ bias,
                        const int* __restrict__ tgt,
                        const float* __restrict__ ws,
                        float* __restrict__ out) {
    int b = blockIdx.x;                    // n*256 + p
    int tid = threadIdx.x;                 // pixel h*16 + w
    int n = b >> 8;
    int p = b & 255;
    int ph = p >> 4, pw = p & 15;
    int h = tid >> 4, w = tid & 15;

    __shared__ float s_area[T_];
    __shared__ int   s_on[T_];
    __shared__ float red[256];

    if (tid < T_) {
        s_on[tid]   = tgt[(n * T_ + tid) * P_ + p];      // target value at pixel p
        s_area[tid] = ws[NB_BASE_ * P_ + n * T_ + tid];
    }
    __syncthreads();

    // base[n,pix] = sum of 16 channel-chunk partials
    float base = 0.f;
    #pragma unroll
    for (int j = 0; j < CHUNKS_; ++j)
        base += ws[(size_t)(n * CHUNKS_ + j) * P_ + tid];

    // m = sigmoid(base + K[ph-h+3, pw-w+3] + b)
    int dh = ph - h + PAD_;
    int dw = pw - w + PAD_;
    float kc = 0.f;
    if ((unsigned)dh < 7u && (unsigned)dw < 7u)
        kc = wt[C_ * 49 + dh * 7 + dw];                  // onehot channel weights
    float xv = base + kc + bias[0];
    float m = 1.f / (1.f + expf(-xv));

    // cnt and first-argmin over areas of "on" targets (jnp.argmin semantics)
    int cnt = 0;
    float best = 3.402823466e38f;
    int idx = 0;
    #pragma unroll
    for (int tt = 0; tt < T_; ++tt) {
        int on = s_on[tt];
        cnt += on;
        if (on > 0 && s_area[tt] < best) { best = s_area[tt]; idx = tt; }
    }

    float contrib;
    if (cnt > 0) {
        float ch = (float)tgt[(n * T_ + idx) * P_ + tid];
        contrib = fabsf(m - ch);
    } else {
        int st = 0;
        #pragma unroll
        for (int tt = 0; tt < T_; ++tt) st += tgt[(n * T_ + tt) * P_ + tid];
        contrib = (float)st * m;
    }

    red[tid] = contrib;
    __syncthreads();
    for (int s = 128; s > 0; s >>= 1) {
        if (tid < s) red[tid] += red[tid + s];
        __syncthreads();
    }
    if (tid == 0) atomicAdd(out, red[0] * (1.0f / 256.0f));
}

extern "C" void kernel_launch(void* const* d_in, const int* in_sizes, int n_in,
                              void* d_out, int out_size, void* d_ws, size_t ws_size,
                              hipStream_t stream) {
    const float* feat = (const float*)d_in[0];
    const float* wt   = (const float*)d_in[1];
    const float* bias = (const float*)d_in[2];
    const int*   tgt  = (const int*)d_in[3];
    float* out = (float*)d_out;
    float* ws  = (float*)d_ws;

    k1_base_areas<<<NB_BASE_ + N_ * T_, 256, 0, stream>>>(feat, wt, tgt, ws, out);
    k2_loss<<<N_ * P_, 256, 0, stream>>>(wt, bias, tgt, ws, out);
}

// Round 3
// 19.916 us; speedup vs baseline: 2.8991x; 2.4967x over previous
//
#include <hip/hip_runtime.h>
#include <math.h>

#define N_    2
#define C_    256
#define H_    16
#define W_    16
#define T_    8
#define P_    256      // H_*W_
#define PAD_  3
#define CPC_  8                    // channels per chunk
#define CHUNKS_ (C_ / CPC_)        // 32
#define NB_BASE_ (N_ * CHUNKS_)    // 64 base blocks
#define ROWS_ 24                   // padded plane is 24x24 (16B-aligned interior)
#define PLSZ_ (ROWS_ * ROWS_)      // 576 floats / channel

// ws layout (floats):
//   base_part[NB_BASE_ * P_] : partial conv sums, (n*CHUNKS_+chunk)*P_ + pix
//   areas[N_*T_]             : at offset NB_BASE_*P_

__global__ void k1_base_areas(const float* __restrict__ feat,
                              const float* __restrict__ wt,
                              const int* __restrict__ tgt,
                              float* __restrict__ ws,
                              float* __restrict__ out) {
    int b = blockIdx.x;
    int tid = threadIdx.x;

    if (b < NB_BASE_) {
        // partial base over CPC_ channels; thread = output pixel; branch-free taps
        __shared__ float pl[CPC_ * PLSZ_];   // 18.4 KB, zero-padded planes
        int n = b / CHUNKS_;
        int chunk = b % CHUNKS_;
        int c0 = chunk * CPC_;

        // zero all planes (halo must be 0)
        float4* z4 = (float4*)pl;
        #pragma unroll
        for (int i = tid; i < CPC_ * PLSZ_ / 4; i += 256)
            z4[i] = make_float4(0.f, 0.f, 0.f, 0.f);
        __syncthreads();

        // stage CPC_ contiguous channel planes into padded interior.
        // interior row starts at col 4 -> every float4 dest is 16B aligned.
        const float4* src4 = (const float4*)(feat + (size_t)(n * C_ + c0) * P_);
        #pragma unroll
        for (int k = 0; k < 2; ++k) {
            int j = tid + k * 256;            // float4 index, 0..511
            int c  = j >> 6;                  // /64 float4 per plane
            int r  = j & 63;
            int hh = r >> 2;
            int w4 = r & 3;
            float4 v = src4[j];
            *(float4*)(pl + c * PLSZ_ + (hh + 3) * ROWS_ + 4 + w4 * 4) = v;
        }
        __syncthreads();

        int h = tid >> 4, w = tid & 15;
        float acc = 0.f;
        #pragma unroll
        for (int c = 0; c < CPC_; ++c) {
            const float* p  = pl + c * PLSZ_ + h * ROWS_ + (w + 1); // (y+3)=h+kh, (x+4)=w+1+kw
            const float* wc = wt + (size_t)(c0 + c) * 49;           // uniform -> scalar loads
            float a = 0.f;
            #pragma unroll
            for (int kh = 0; kh < 7; ++kh)
                #pragma unroll
                for (int kw = 0; kw < 7; ++kw)
                    a += p[kh * ROWS_ + kw] * wc[kh * 7 + kw];
            acc += a;
        }
        ws[(size_t)b * P_ + tid] = acc;
    } else {
        // areas[n,tt]
        __shared__ float red[256];
        int i = b - NB_BASE_;              // 0..15
        int n = i >> 3, tt = i & 7;
        float v = (float)tgt[(n * T_ + tt) * P_ + tid];
        #pragma unroll
        for (int off = 32; off; off >>= 1) v += __shfl_down(v, off, 64);
        if ((tid & 63) == 0) red[tid >> 6] = v;
        __syncthreads();
        if (tid == 0) {
            ws[NB_BASE_ * P_ + i] = red[0] + red[1] + red[2] + red[3];
            if (i == 0) out[0] = 0.f;      // re-zero scalar output every launch
        }
    }
}

__global__ void k2_loss(const float* __restrict__ wt,
                        const float* __restrict__ bias,
                        const int* __restrict__ tgt,
                        const float* __restrict__ ws,
                        float* __restrict__ out) {
    int b = blockIdx.x;                    // n*256 + p
    int tid = threadIdx.x;                 // pixel h*16 + w
    int n = b >> 8;
    int p = b & 255;
    int ph = p >> 4, pw = p & 15;
    int h = tid >> 4, w = tid & 15;

    __shared__ float s_area[T_];
    __shared__ int   s_on[T_];
    __shared__ float wred[4];

    if (tid < T_) {
        s_on[tid]   = tgt[(n * T_ + tid) * P_ + p];
        s_area[tid] = ws[NB_BASE_ * P_ + n * T_ + tid];
    }
    __syncthreads();

    // base = sum of CHUNKS_ partials (coalesced, L2-resident)
    float base = 0.f;
    #pragma unroll
    for (int j = 0; j < CHUNKS_; ++j)
        base += ws[(size_t)(n * CHUNKS_ + j) * P_ + tid];

    int dh = ph - h + PAD_;
    int dw = pw - w + PAD_;
    float kc = 0.f;
    if ((unsigned)dh < 7u && (unsigned)dw < 7u)
        kc = wt[C_ * 49 + dh * 7 + dw];
    float m = 1.f / (1.f + expf(-(base + kc + bias[0])));

    int cnt = 0;
    float best = 3.402823466e38f;
    int idx = 0;
    #pragma unroll
    for (int tt = 0; tt < T_; ++tt) {
        int on = s_on[tt];
        cnt += on;
        if (on > 0 && s_area[tt] < best) { best = s_area[tt]; idx = tt; }
    }

    float contrib;                          // cnt/idx are block-uniform -> no divergence
    if (cnt > 0) {
        contrib = fabsf(m - (float)tgt[(n * T_ + idx) * P_ + tid]);
    } else {
        int st = 0;
        #pragma unroll
        for (int tt = 0; tt < T_; ++tt) st += tgt[(n * T_ + tt) * P_ + tid];
        contrib = (float)st * m;
    }

    #pragma unroll
    for (int off = 32; off; off >>= 1) contrib += __shfl_down(contrib, off, 64);
    if ((tid & 63) == 0) wred[tid >> 6] = contrib;
    __syncthreads();
    if (tid == 0)
        atomicAdd(out, (wred[0] + wred[1] + wred[2] + wred[3]) * (1.0f / 256.0f));
}

extern "C" void kernel_launch(void* const* d_in, const int* in_sizes, int n_in,
                              void* d_out, int out_size, void* d_ws, size_t ws_size,
                              hipStream_t stream) {
    const float* feat = (const float*)d_in[0];
    const float* wt   = (const float*)d_in[1];
    const float* bias = (const float*)d_in[2];
    const int*   tgt  = (const int*)d_in[3];
    float* out = (float*)d_out;
    float* ws  = (float*)d_ws;

    k1_base_areas<<<NB_BASE_ + N_ * T_, 256, 0, stream>>>(feat, wt, tgt, ws, out);
    k2_loss<<<N_ * P_, 256, 0, stream>>>(wt, bias, tgt, ws, out);
}

// Round 4
// 16.159 us; speedup vs baseline: 3.5731x; 1.2325x over previous
//
#include <hip/hip_runtime.h>
#include <math.h>

#define N_    2
#define C_    256
#define H_    16
#define W_    16
#define T_    8
#define P_    256      // H_*W_
#define PAD_  3
#define CPC_  4                    // channels per chunk
#define CHUNKS_ (C_ / CPC_)        // 64
#define NB_BASE_ (N_ * CHUNKS_)    // 128 conv blocks
#define ROWS_ 24                   // padded plane 24x24, 16B-aligned interior
#define PLSZ_ (ROWS_ * ROWS_)      // 576 floats / channel

// ws layout (floats): base_part[NB_BASE_ * P_], (n*CHUNKS_+chunk)*P_ + pix

__global__ void k1_conv(const float* __restrict__ feat,
                        const float* __restrict__ wt,
                        float* __restrict__ ws,
                        float* __restrict__ out) {
    int b = blockIdx.x;                  // n*CHUNKS_ + chunk
    int tid = threadIdx.x;
    __shared__ float pl[CPC_ * PLSZ_];   // 9.2 KB zero-padded planes
    __shared__ float wsm[CPC_ * 49];     // 784 B weights

    int n = b / CHUNKS_;
    int chunk = b % CHUNKS_;
    int c0 = chunk * CPC_;

    // zero planes (halo must be 0); weights to LDS (independent of zeroing)
    float4* z4 = (float4*)pl;
    #pragma unroll
    for (int i = tid; i < CPC_ * PLSZ_ / 4; i += 256)
        z4[i] = make_float4(0.f, 0.f, 0.f, 0.f);
    if (tid < CPC_ * 49) wsm[tid] = wt[c0 * 49 + tid];
    __syncthreads();

    // stage 4 contiguous channel planes: 1024 floats = 256 float4 = 1/thread
    {
        const float4* src4 = (const float4*)(feat + (size_t)(n * C_ + c0) * P_);
        int c  = tid >> 6;               // float4s per plane = 64
        int r  = tid & 63;
        int hh = r >> 2;
        int w4 = r & 3;
        *(float4*)(pl + c * PLSZ_ + (hh + 3) * ROWS_ + 4 + w4 * 4) = src4[tid];
    }
    __syncthreads();

    int h = tid >> 4, w = tid & 15;
    float acc[CPC_];
    #pragma unroll
    for (int c = 0; c < CPC_; ++c) acc[c] = 0.f;

    #pragma unroll
    for (int c = 0; c < CPC_; ++c) {
        const float* p  = pl + c * PLSZ_ + h * ROWS_ + (w + 1);
        const float* wc = wsm + c * 49;
        #pragma unroll
        for (int kh = 0; kh < 7; ++kh)
            #pragma unroll
            for (int kw = 0; kw < 7; ++kw)
                acc[c] += p[kh * ROWS_ + kw] * wc[kh * 7 + kw];
    }
    ws[(size_t)b * P_ + tid] = (acc[0] + acc[1]) + (acc[2] + acc[3]);

    if (b == 0 && tid == 0) out[0] = 0.f;   // re-zero scalar output every launch
}

__global__ __launch_bounds__(1024)
void k2_loss(const float* __restrict__ wt,
             const float* __restrict__ bias,
             const int* __restrict__ tgt,
             const float* __restrict__ ws,
             float* __restrict__ out) {
    int b = blockIdx.x;                    // n*16 + pgroup
    int tid = threadIdx.x;                 // 0..1023
    int n = b >> 4, pg = b & 15;

    __shared__ float s_tgt[T_][P_];        // 8 KB target planes (as float)
    __shared__ float s_ktab[49];
    __shared__ float s_area[T_];
    __shared__ float s_st[P_];             // sum_t tgt[t][pix]
    __shared__ int   s_cnt[16];
    __shared__ int   s_idx[16];
    __shared__ float s_red[16];

    // stage targets (2048 ints) + onehot-channel weight table
    for (int i = tid; i < T_ * P_; i += 1024)
        s_tgt[0][i] = (float)tgt[n * T_ * P_ + i];
    if (tid < 49) s_ktab[tid] = wt[C_ * 49 + tid];
    __syncthreads();

    int wave = tid >> 6, lane = tid & 63;
    if (wave < 8) {
        // area for target t=wave
        float v = s_tgt[wave][lane] + s_tgt[wave][lane + 64]
                + s_tgt[wave][lane + 128] + s_tgt[wave][lane + 192];
        #pragma unroll
        for (int off = 32; off; off >>= 1) v += __shfl_down(v, off, 64);
        if (lane == 0) s_area[wave] = v;
    } else if (wave < 12) {
        int pix = tid - 512;               // 0..255
        float s = 0.f;
        #pragma unroll
        for (int t = 0; t < T_; ++t) s += s_tgt[t][pix];
        s_st[pix] = s;
    }
    __syncthreads();

    if (tid < 16) {                        // per-p cnt + first-argmin
        int p = pg * 16 + tid;
        int cnt = 0; float best = 3.402823466e38f; int idx = 0;
        #pragma unroll
        for (int t = 0; t < T_; ++t) {
            float on = s_tgt[t][p];
            cnt += (int)on;
            if (on > 0.f && s_area[t] < best) { best = s_area[t]; idx = t; }
        }
        s_cnt[tid] = cnt; s_idx[tid] = idx;
    }
    __syncthreads();

    int slot = tid >> 8;                   // 0..3
    int pix  = tid & 255;
    int h = pix >> 4, wcol = pix & 15;

    // base computed once per thread, reused for 4 p's
    float base = 0.f;
    const float* wsb = ws + (size_t)n * CHUNKS_ * P_ + pix;
    #pragma unroll
    for (int j = 0; j < CHUNKS_; ++j) base += wsb[j * P_];
    float bv = bias[0];
    float st = s_st[pix];

    float lsum = 0.f;
    #pragma unroll
    for (int it = 0; it < 4; ++it) {
        int pl_ = it * 4 + slot;           // wave-uniform
        int p = pg * 16 + pl_;
        int ph = p >> 4, pw = p & 15;
        int dh = ph - h + PAD_, dw = pw - wcol + PAD_;
        float kc = ((unsigned)dh < 7u && (unsigned)dw < 7u) ? s_ktab[dh * 7 + dw] : 0.f;
        float m = 1.f / (1.f + expf(-(base + kc + bv)));
        float contrib;
        if (s_cnt[pl_] > 0) contrib = fabsf(m - s_tgt[s_idx[pl_]][pix]);
        else                contrib = st * m;
        lsum += contrib;
    }

    #pragma unroll
    for (int off = 32; off; off >>= 1) lsum += __shfl_down(lsum, off, 64);
    if (lane == 0) s_red[wave] = lsum;
    __syncthreads();
    if (tid == 0) {
        float s = 0.f;
        #pragma unroll
        for (int i = 0; i < 16; ++i) s += s_red[i];
        atomicAdd(out, s * (1.0f / 256.0f));
    }
}

extern "C" void kernel_launch(void* const* d_in, const int* in_sizes, int n_in,
                              void* d_out, int out_size, void* d_ws, size_t ws_size,
                              hipStream_t stream) {
    const float* feat = (const float*)d_in[0];
    const float* wt   = (const float*)d_in[1];
    const float* bias = (const float*)d_in[2];
    const int*   tgt  = (const int*)d_in[3];
    float* out = (float*)d_out;
    float* ws  = (float*)d_ws;

    k1_conv<<<NB_BASE_, 256, 0, stream>>>(feat, wt, ws, out);
    k2_loss<<<N_ * 16, 1024, 0, stream>>>(wt, bias, tgt, ws, out);
}